// Round 1
// baseline (198.023 us; speedup 1.0000x reference)
//
#include <hip/hip_runtime.h>

// Graph transformer block, exploiting multiplicative adjacency masking:
//   softmax_row_i = [ (N - deg_i)*1-weights + e^{s_ij} on edges ]
//   out_i = (Vsum + sum_edges (e^s - 1) V_j) / (N + sum_edges (e^s - 1))
// Pipeline: prep(bf16 cast) -> proj_gemm (bf16 MFMA) -> vsum -> sparse main pass.

#define NN  8192
#define DIM 256
#define SCALE 0.0625f   // 1/sqrt(256)

typedef __attribute__((ext_vector_type(8))) short short8;
typedef __attribute__((ext_vector_type(4))) float f32x4;

__device__ __forceinline__ unsigned short f2bf(float f) {
    union { float f; unsigned u; } v; v.f = f;
    unsigned u = v.u;
    unsigned r = (u + 0x7fffu + ((u >> 16) & 1u)) >> 16;   // RNE
    return (unsigned short)r;
}
__device__ __forceinline__ float bf2f(unsigned short s) {
    union { unsigned u; float f; } v; v.u = ((unsigned)s) << 16;
    return v.f;
}

// ---------------------------------------------------------------- prep: fp32 -> bf16
__global__ __launch_bounds__(256) void prep_kernel(
    const float* __restrict__ h, const float* __restrict__ Wq,
    const float* __restrict__ Wk, const float* __restrict__ Wv,
    unsigned short* __restrict__ h_bf, unsigned short* __restrict__ w_bf)
{
    int b = blockIdx.x, t = threadIdx.x;
    if (b < 2048) {
        int idx = (b * 256 + t) * 4;               // h: 2,097,152 elems
        float4 v = *(const float4*)(h + idx);
        ushort4 o; o.x = f2bf(v.x); o.y = f2bf(v.y); o.z = f2bf(v.z); o.w = f2bf(v.w);
        *(ushort4*)(h_bf + idx) = o;
    } else {
        int idx = ((b - 2048) * 256 + t) * 4;      // W: 196,608 elems (3 x 65536)
        int w = idx >> 16;
        int offn = idx & 65535;
        const float* src = (w == 0) ? Wq : (w == 1) ? Wk : Wv;
        float4 v = *(const float4*)(src + offn);
        ushort4 o; o.x = f2bf(v.x); o.y = f2bf(v.y); o.z = f2bf(v.z); o.w = f2bf(v.w);
        *(ushort4*)(w_bf + idx) = o;
    }
}

// ---------------------------------------------------------------- projections via bf16 MFMA
// C[m,n] = sum_k h[m,k] * W[n,k];  grid = (128 m-blocks of 64 rows, 3 projections)
__global__ __launch_bounds__(256) void proj_gemm(
    const unsigned short* __restrict__ h_bf, const unsigned short* __restrict__ w_bf,
    float* __restrict__ Q, unsigned short* __restrict__ Kb, unsigned short* __restrict__ Vb)
{
    __shared__ unsigned short sB[256][40];         // [n][k-chunk], +8 pad vs bank conflicts
    const int mb = blockIdx.x, p = blockIdx.y;
    const unsigned short* W = w_bf + (p << 16);
    const int tid = threadIdx.x, wave = tid >> 6, lane = tid & 63;

    f32x4 acc[16];
#pragma unroll
    for (int f = 0; f < 16; ++f) acc[f] = (f32x4)(0.0f);

    const int arow = mb * 64 + wave * 16 + (lane & 15);
    const int ko   = (lane >> 4) * 8;

    for (int kk = 0; kk < 256; kk += 32) {
        __syncthreads();
        {   // stage W[:, kk:kk+32] -> sB  (each thread: one n-row, 32 ushorts = 4x uint4)
            const uint4* src = (const uint4*)(W + tid * 256 + kk);
            uint4* dst = (uint4*)(&sB[tid][0]);
            dst[0] = src[0]; dst[1] = src[1]; dst[2] = src[2]; dst[3] = src[3];
        }
        __syncthreads();
        short8 a = *(const short8*)(h_bf + (size_t)arow * 256 + kk + ko);
#pragma unroll
        for (int f = 0; f < 16; ++f) {
            short8 b = *(const short8*)(&sB[f * 16 + (lane & 15)][ko]);
            acc[f] = __builtin_amdgcn_mfma_f32_16x16x32_bf16(a, b, acc[f], 0, 0, 0);
        }
    }

    const int orow = mb * 64 + wave * 16 + ((lane >> 4) << 2);
    const int ocol = lane & 15;
    if (p == 0) {
#pragma unroll
        for (int f = 0; f < 16; ++f)
#pragma unroll
            for (int r = 0; r < 4; ++r)
                Q[(size_t)(orow + r) * 256 + f * 16 + ocol] = acc[f][r];
    } else {
        unsigned short* dstb = (p == 1) ? Kb : Vb;
#pragma unroll
        for (int f = 0; f < 16; ++f)
#pragma unroll
            for (int r = 0; r < 4; ++r)
                dstb[(size_t)(orow + r) * 256 + f * 16 + ocol] = f2bf(acc[f][r]);
    }
}

// ---------------------------------------------------------------- Vsum = column sums of V
__global__ __launch_bounds__(256) void vsum_partial(
    const unsigned short* __restrict__ Vb, float* __restrict__ partial)
{
    int b = blockIdx.x, t = threadIdx.x;   // 128 blocks x 64 rows
    float s = 0.0f;
    for (int r = 0; r < 64; ++r)
        s += bf2f(Vb[(size_t)(b * 64 + r) * 256 + t]);
    partial[b * 256 + t] = s;
}
__global__ __launch_bounds__(256) void vsum_final(
    const float* __restrict__ partial, float* __restrict__ Vsum)
{
    int t = threadIdx.x;
    float s = 0.0f;
    for (int b = 0; b < 128; ++b) s += partial[b * 256 + t];
    Vsum[t] = s;
}

// ---------------------------------------------------------------- main sparse pass
// One block per row i. Phase A: stream adj row, per-wave ballot-compact edge cols.
// Phase B: per-edge dot(Q_i, K_j) wave-parallel over the 256 dims. Phase C: axpy V.
__global__ __launch_bounds__(256) void attn_main(
    const float* __restrict__ adj, const float* __restrict__ Q,
    const unsigned short* __restrict__ Kb, const unsigned short* __restrict__ Vb,
    const float* __restrict__ Vsum, float* __restrict__ out)
{
    __shared__ int   s_idx[4 * 512];
    __shared__ float s_e[4 * 512];
    __shared__ int   s_wcnt[4];

    const int i    = blockIdx.x;
    const int tid  = threadIdx.x;
    const int lane = tid & 63;
    const int wave = tid >> 6;
    const int segbase = wave * 512;

    // ---- Phase A: deterministic (ballot-ordered) compaction, no atomics
    const float4* arow = (const float4*)(adj + (size_t)i * NN);
    const unsigned long long lt = (1ull << lane) - 1ull;
    int off = 0;
#pragma unroll
    for (int it = 0; it < 8; ++it) {
        int c4 = wave * 512 + it * 64 + lane;      // float4 index in row (0..2047)
        float4 v = arow[c4];
        int col = c4 * 4;
        {
            bool nz = (v.x != 0.0f);
            unsigned long long m = __ballot(nz);
            if (nz) s_idx[segbase + off + __popcll(m & lt)] = col;
            off += __popcll(m);
        }
        {
            bool nz = (v.y != 0.0f);
            unsigned long long m = __ballot(nz);
            if (nz) s_idx[segbase + off + __popcll(m & lt)] = col + 1;
            off += __popcll(m);
        }
        {
            bool nz = (v.z != 0.0f);
            unsigned long long m = __ballot(nz);
            if (nz) s_idx[segbase + off + __popcll(m & lt)] = col + 2;
            off += __popcll(m);
        }
        {
            bool nz = (v.w != 0.0f);
            unsigned long long m = __ballot(nz);
            if (nz) s_idx[segbase + off + __popcll(m & lt)] = col + 3;
            off += __popcll(m);
        }
    }
    if (lane == 0) s_wcnt[wave] = off;   // off is wave-uniform

    // ---- Phase B: e_k = exp(scale * Q_i . K_j) - 1   (wave handles its own segment)
    const float4 q = ((const float4*)(Q + (size_t)i * DIM))[lane];  // d = lane*4..+4
    for (int k = 0; k < off; ++k) {
        int j = s_idx[segbase + k];
        ushort4 kb = ((const ushort4*)(Kb + (size_t)j * DIM))[lane];
        float d = q.x * bf2f(kb.x) + q.y * bf2f(kb.y)
                + q.z * bf2f(kb.z) + q.w * bf2f(kb.w);
#pragma unroll
        for (int m = 1; m < 64; m <<= 1) d += __shfl_xor(d, m);
        if (lane == 0) s_e[segbase + k] = __expf(SCALE * d) - 1.0f;
    }
    __syncthreads();

    // ---- Phase C: accumulate over all segments (deterministic order)
    float acc = 0.0f, den = 0.0f;
    for (int w = 0; w < 4; ++w) {
        int cnt = s_wcnt[w];
#pragma unroll 4
        for (int k = 0; k < cnt; ++k) {
            float e = s_e[w * 512 + k];
            int j = s_idx[w * 512 + k];
            acc += e * bf2f(Vb[(size_t)j * DIM + tid]);
            den += e;
        }
    }
    out[(size_t)i * DIM + tid] = (Vsum[tid] + acc) / (8192.0f + den);
}

// ---------------------------------------------------------------- host
extern "C" void kernel_launch(void* const* d_in, const int* in_sizes, int n_in,
                              void* d_out, int out_size, void* d_ws, size_t ws_size,
                              hipStream_t stream)
{
    const float* adj = (const float*)d_in[0];
    const float* h   = (const float*)d_in[1];
    const float* Wq  = (const float*)d_in[2];
    const float* Wk  = (const float*)d_in[3];
    const float* Wv  = (const float*)d_in[4];
    float* out = (float*)d_out;

    char* ws = (char*)d_ws;
    // workspace layout (~20.6 MB total)
    unsigned short* h_bf = (unsigned short*)(ws);                          // 4 MiB
    unsigned short* w_bf = (unsigned short*)(ws + (4u << 20));             // 384 KiB (slot 512K)
    float*          Qf   = (float*)         (ws + (4u << 20) + (512u << 10)); // 8 MiB
    unsigned short* Kb   = (unsigned short*)(ws + (12u << 20) + (512u << 10) + (256u << 10)); // below
    // recompute offsets explicitly to avoid arithmetic slips:
    size_t off = 0;
    unsigned short* p_hbf = (unsigned short*)(ws + off); off += (size_t)NN * DIM * 2;       // 4,194,304
    unsigned short* p_wbf = (unsigned short*)(ws + off); off += (size_t)3 * DIM * DIM * 2;  // +393,216
    off = (off + 1023) & ~(size_t)1023;
    float*          p_Q   = (float*)(ws + off);          off += (size_t)NN * DIM * 4;       // +8,388,608
    unsigned short* p_Kb  = (unsigned short*)(ws + off); off += (size_t)NN * DIM * 2;       // +4,194,304
    unsigned short* p_Vb  = (unsigned short*)(ws + off); off += (size_t)NN * DIM * 2;       // +4,194,304
    float*          p_par = (float*)(ws + off);          off += (size_t)128 * DIM * 4;      // +131,072
    float*          p_vs  = (float*)(ws + off);          off += DIM * 4;                    // +1,024
    (void)h_bf; (void)w_bf; (void)Qf; (void)Kb; (void)ws_size; (void)in_sizes; (void)n_in; (void)out_size;

    prep_kernel<<<2240, 256, 0, stream>>>(h, Wq, Wk, Wv, p_hbf, p_wbf);
    proj_gemm<<<dim3(128, 3), 256, 0, stream>>>(p_hbf, p_wbf, p_Q, p_Kb, p_Vb);
    vsum_partial<<<128, 256, 0, stream>>>(p_Vb, p_par);
    vsum_final<<<1, 256, 0, stream>>>(p_par, p_vs);
    attn_main<<<NN, 256, 0, stream>>>(adj, p_Q, p_Kb, p_Vb, p_vs, out);
}

// Round 2
// 133.609 us; speedup vs baseline: 1.4821x; 1.4821x over previous
//
#include <hip/hip_runtime.h>

// Graph transformer block, exploiting multiplicative adjacency masking:
//   out_i = (Vsum + sum_edges (e^{s}-1) V_j) / (N + sum_edges (e^{s}-1))
// Pipeline: prep(bf16 cast) -> proj_gemm (bf16 MFMA) -> vsum -> sparse main pass.

#define NN  8192
#define DIM 256
#define SCALE 0.0625f   // 1/sqrt(256)
#define CAP 128         // per-wave-segment edge capacity (mean 20.5, 6-sigma ~45)

typedef __attribute__((ext_vector_type(8))) short short8;
typedef __attribute__((ext_vector_type(4))) float f32x4;
typedef __attribute__((ext_vector_type(4))) unsigned int u32x4;

__device__ __forceinline__ unsigned short f2bf(float f) {
    union { float f; unsigned u; } v; v.f = f;
    unsigned u = v.u;
    unsigned r = (u + 0x7fffu + ((u >> 16) & 1u)) >> 16;   // RNE
    return (unsigned short)r;
}
__device__ __forceinline__ float bf2f(unsigned short s) {
    union { unsigned u; float f; } v; v.u = ((unsigned)s) << 16;
    return v.f;
}
__device__ __forceinline__ float dw_lo(unsigned u) {
    union { unsigned u; float f; } v; v.u = u << 16; return v.f;
}
__device__ __forceinline__ float dw_hi(unsigned u) {
    union { unsigned u; float f; } v; v.u = u & 0xffff0000u; return v.f;
}

// ---------------------------------------------------------------- prep: fp32 -> bf16
__global__ __launch_bounds__(256) void prep_kernel(
    const float* __restrict__ h, const float* __restrict__ Wq,
    const float* __restrict__ Wk, const float* __restrict__ Wv,
    unsigned short* __restrict__ h_bf, unsigned short* __restrict__ w_bf)
{
    int b = blockIdx.x, t = threadIdx.x;
    if (b < 2048) {
        int idx = (b * 256 + t) * 4;               // h: 2,097,152 elems
        float4 v = *(const float4*)(h + idx);
        ushort4 o; o.x = f2bf(v.x); o.y = f2bf(v.y); o.z = f2bf(v.z); o.w = f2bf(v.w);
        *(ushort4*)(h_bf + idx) = o;
    } else {
        int idx = ((b - 2048) * 256 + t) * 4;      // W: 196,608 elems (3 x 65536)
        int w = idx >> 16;
        int offn = idx & 65535;
        const float* src = (w == 0) ? Wq : (w == 1) ? Wk : Wv;
        float4 v = *(const float4*)(src + offn);
        ushort4 o; o.x = f2bf(v.x); o.y = f2bf(v.y); o.z = f2bf(v.z); o.w = f2bf(v.w);
        *(ushort4*)(w_bf + idx) = o;
    }
}

// ---------------------------------------------------------------- projections via bf16 MFMA
__global__ __launch_bounds__(256) void proj_gemm(
    const unsigned short* __restrict__ h_bf, const unsigned short* __restrict__ w_bf,
    float* __restrict__ Q, unsigned short* __restrict__ Kb, unsigned short* __restrict__ Vb)
{
    __shared__ unsigned short sB[256][40];
    const int mb = blockIdx.x, p = blockIdx.y;
    const unsigned short* W = w_bf + (p << 16);
    const int tid = threadIdx.x, wave = tid >> 6, lane = tid & 63;

    f32x4 acc[16];
#pragma unroll
    for (int f = 0; f < 16; ++f) acc[f] = (f32x4)(0.0f);

    const int arow = mb * 64 + wave * 16 + (lane & 15);
    const int ko   = (lane >> 4) * 8;

    for (int kk = 0; kk < 256; kk += 32) {
        __syncthreads();
        {
            const uint4* src = (const uint4*)(W + tid * 256 + kk);
            uint4* dst = (uint4*)(&sB[tid][0]);
            dst[0] = src[0]; dst[1] = src[1]; dst[2] = src[2]; dst[3] = src[3];
        }
        __syncthreads();
        short8 a = *(const short8*)(h_bf + (size_t)arow * 256 + kk + ko);
#pragma unroll
        for (int f = 0; f < 16; ++f) {
            short8 b = *(const short8*)(&sB[f * 16 + (lane & 15)][ko]);
            acc[f] = __builtin_amdgcn_mfma_f32_16x16x32_bf16(a, b, acc[f], 0, 0, 0);
        }
    }

    const int orow = mb * 64 + wave * 16 + ((lane >> 4) << 2);
    const int ocol = lane & 15;
    if (p == 0) {
#pragma unroll
        for (int f = 0; f < 16; ++f)
#pragma unroll
            for (int r = 0; r < 4; ++r)
                Q[(size_t)(orow + r) * 256 + f * 16 + ocol] = acc[f][r];
    } else {
        unsigned short* dstb = (p == 1) ? Kb : Vb;
#pragma unroll
        for (int f = 0; f < 16; ++f)
#pragma unroll
            for (int r = 0; r < 4; ++r)
                dstb[(size_t)(orow + r) * 256 + f * 16 + ocol] = f2bf(acc[f][r]);
    }
}

// ---------------------------------------------------------------- Vsum = column sums of V
__global__ __launch_bounds__(256) void vsum_partial(
    const unsigned short* __restrict__ Vb, float* __restrict__ partial)
{
    int b = blockIdx.x, t = threadIdx.x;
    float s = 0.0f;
    for (int r = 0; r < 64; ++r)
        s += bf2f(Vb[(size_t)(b * 64 + r) * 256 + t]);
    partial[b * 256 + t] = s;
}
__global__ __launch_bounds__(256) void vsum_final(
    const float* __restrict__ partial, float* __restrict__ Vsum)
{
    int t = threadIdx.x;
    float s = 0.0f;
    for (int b = 0; b < 128; ++b) s += partial[b * 256 + t];
    Vsum[t] = s;
}

// ---------------------------------------------------------------- main sparse pass
// One block per row i. Phase A: preloaded nontemporal adj stream + ballot compact.
// Phase B+C fused per wave: 4 edges per round; 16-lane group computes one edge's
// 256-dim dot (16 dims/lane, 4-step shuffle reduce); all lanes axpy 4 V rows.
__global__ __launch_bounds__(256) void attn_main(
    const float* __restrict__ adj, const float* __restrict__ Q,
    const unsigned short* __restrict__ Kb, const unsigned short* __restrict__ Vb,
    const float* __restrict__ Vsum, float* __restrict__ out)
{
    __shared__ int   s_idx[4][CAP];
    __shared__ float s_acc[4][256];
    __shared__ float s_den[4];

    const int i    = blockIdx.x;
    const int tid  = threadIdx.x;
    const int lane = tid & 63;
    const int wave = tid >> 6;

    // ---- Phase A: batched nontemporal loads, then ballot-ordered compaction
    const f32x4* arow = (const f32x4*)(adj + (size_t)i * NN);
    f32x4 av[8];
#pragma unroll
    for (int it = 0; it < 8; ++it)
        av[it] = __builtin_nontemporal_load(arow + (wave * 512 + it * 64 + lane));

    const unsigned long long lt = (1ull << lane) - 1ull;
    int off = 0;
#pragma unroll
    for (int it = 0; it < 8; ++it) {
        const int colbase = (wave * 512 + it * 64 + lane) * 4;
#pragma unroll
        for (int c = 0; c < 4; ++c) {
            bool nz = (av[it][c] != 0.0f);
            unsigned long long m = __ballot(nz);
            if (nz) s_idx[wave][off + __popcll(m & lt)] = colbase + c;
            off += __popcll(m);
        }
    }

    // ---- Q chunk for the dot: dims (lane&15)*16 .. +15
    const float* Qi = Q + (size_t)i * DIM + (lane & 15) * 16;
    f32x4 q0 = *(const f32x4*)(Qi);
    f32x4 q1 = *(const f32x4*)(Qi + 4);
    f32x4 q2 = *(const f32x4*)(Qi + 8);
    f32x4 q3 = *(const f32x4*)(Qi + 12);

    const int g = lane >> 4;
    float acc0 = 0.f, acc1 = 0.f, acc2 = 0.f, acc3 = 0.f, den = 0.f;
    const int rounds = (off + 3) >> 2;

#pragma unroll 2
    for (int r = 0; r < rounds; ++r) {
        const int kb0 = r * 4;
        int jg0 = (kb0 + 0 < off) ? s_idx[wave][kb0 + 0] : 0;
        int jg1 = (kb0 + 1 < off) ? s_idx[wave][kb0 + 1] : 0;
        int jg2 = (kb0 + 2 < off) ? s_idx[wave][kb0 + 2] : 0;
        int jg3 = (kb0 + 3 < off) ? s_idx[wave][kb0 + 3] : 0;

        const bool myv = (kb0 + g) < off;
        const int  myj = (g == 0) ? jg0 : (g == 1) ? jg1 : (g == 2) ? jg2 : jg3;

        const u32x4* kp = (const u32x4*)(Kb + (size_t)myj * DIM + (lane & 15) * 16);
        u32x4 ka = kp[0];
        u32x4 kc = kp[1];

        ushort4 v0 = *(const ushort4*)(Vb + (size_t)jg0 * DIM + lane * 4);
        ushort4 v1 = *(const ushort4*)(Vb + (size_t)jg1 * DIM + lane * 4);
        ushort4 v2 = *(const ushort4*)(Vb + (size_t)jg2 * DIM + lane * 4);
        ushort4 v3 = *(const ushort4*)(Vb + (size_t)jg3 * DIM + lane * 4);

        // 16-dim partial dot (4 independent chains)
        float d0 = q0[0] * dw_lo(ka[0]);
        float d1 = q0[1] * dw_hi(ka[0]);
        float d2 = q0[2] * dw_lo(ka[1]);
        float d3 = q0[3] * dw_hi(ka[1]);
        d0 = fmaf(q1[0], dw_lo(ka[2]), d0);
        d1 = fmaf(q1[1], dw_hi(ka[2]), d1);
        d2 = fmaf(q1[2], dw_lo(ka[3]), d2);
        d3 = fmaf(q1[3], dw_hi(ka[3]), d3);
        d0 = fmaf(q2[0], dw_lo(kc[0]), d0);
        d1 = fmaf(q2[1], dw_hi(kc[0]), d1);
        d2 = fmaf(q2[2], dw_lo(kc[1]), d2);
        d3 = fmaf(q2[3], dw_hi(kc[1]), d3);
        d0 = fmaf(q3[0], dw_lo(kc[2]), d0);
        d1 = fmaf(q3[1], dw_hi(kc[2]), d1);
        d2 = fmaf(q3[2], dw_lo(kc[3]), d2);
        d3 = fmaf(q3[3], dw_hi(kc[3]), d3);
        float d = (d0 + d1) + (d2 + d3);

        // reduce across the 16-lane group
        d += __shfl_xor(d, 1);
        d += __shfl_xor(d, 2);
        d += __shfl_xor(d, 4);
        d += __shfl_xor(d, 8);

        float e = myv ? (__expf(SCALE * d) - 1.0f) : 0.0f;

        float e0 = __shfl(e, 0);
        float e1 = __shfl(e, 16);
        float e2 = __shfl(e, 32);
        float e3 = __shfl(e, 48);
        den += (e0 + e1) + (e2 + e3);

        acc0 = fmaf(e0, bf2f(v0.x), acc0); acc1 = fmaf(e0, bf2f(v0.y), acc1);
        acc2 = fmaf(e0, bf2f(v0.z), acc2); acc3 = fmaf(e0, bf2f(v0.w), acc3);
        acc0 = fmaf(e1, bf2f(v1.x), acc0); acc1 = fmaf(e1, bf2f(v1.y), acc1);
        acc2 = fmaf(e1, bf2f(v1.z), acc2); acc3 = fmaf(e1, bf2f(v1.w), acc3);
        acc0 = fmaf(e2, bf2f(v2.x), acc0); acc1 = fmaf(e2, bf2f(v2.y), acc1);
        acc2 = fmaf(e2, bf2f(v2.z), acc2); acc3 = fmaf(e2, bf2f(v2.w), acc3);
        acc0 = fmaf(e3, bf2f(v3.x), acc0); acc1 = fmaf(e3, bf2f(v3.y), acc1);
        acc2 = fmaf(e3, bf2f(v3.z), acc2); acc3 = fmaf(e3, bf2f(v3.w), acc3);
    }

    // ---- cross-wave reduction
    f32x4 accv = {acc0, acc1, acc2, acc3};
    *(f32x4*)(&s_acc[wave][lane * 4]) = accv;
    if (lane == 0) s_den[wave] = den;
    __syncthreads();

    float a = (s_acc[0][tid] + s_acc[1][tid]) + (s_acc[2][tid] + s_acc[3][tid]);
    float dn = (s_den[0] + s_den[1]) + (s_den[2] + s_den[3]);
    out[(size_t)i * DIM + tid] = (Vsum[tid] + a) / (8192.0f + dn);
}

// ---------------------------------------------------------------- host
extern "C" void kernel_launch(void* const* d_in, const int* in_sizes, int n_in,
                              void* d_out, int out_size, void* d_ws, size_t ws_size,
                              hipStream_t stream)
{
    const float* adj = (const float*)d_in[0];
    const float* h   = (const float*)d_in[1];
    const float* Wq  = (const float*)d_in[2];
    const float* Wk  = (const float*)d_in[3];
    const float* Wv  = (const float*)d_in[4];
    float* out = (float*)d_out;

    char* ws = (char*)d_ws;
    size_t off = 0;
    unsigned short* p_hbf = (unsigned short*)(ws + off); off += (size_t)NN * DIM * 2;
    unsigned short* p_wbf = (unsigned short*)(ws + off); off += (size_t)3 * DIM * DIM * 2;
    off = (off + 1023) & ~(size_t)1023;
    float*          p_Q   = (float*)(ws + off);          off += (size_t)NN * DIM * 4;
    unsigned short* p_Kb  = (unsigned short*)(ws + off); off += (size_t)NN * DIM * 2;
    unsigned short* p_Vb  = (unsigned short*)(ws + off); off += (size_t)NN * DIM * 2;
    float*          p_par = (float*)(ws + off);          off += (size_t)128 * DIM * 4;
    float*          p_vs  = (float*)(ws + off);          off += DIM * 4;
    (void)ws_size; (void)in_sizes; (void)n_in; (void)out_size;

    prep_kernel<<<2240, 256, 0, stream>>>(h, Wq, Wk, Wv, p_hbf, p_wbf);
    proj_gemm<<<dim3(128, 3), 256, 0, stream>>>(p_hbf, p_wbf, p_Q, p_Kb, p_Vb);
    vsum_partial<<<128, 256, 0, stream>>>(p_Vb, p_par);
    vsum_final<<<1, 256, 0, stream>>>(p_par, p_vs);
    attn_main<<<NN, 256, 0, stream>>>(adj, p_Q, p_Kb, p_Vb, p_vs, out);
}